// Round 1
// 1815.718 us; speedup vs baseline: 1.0392x; 1.0392x over previous
//
#include <hip/hip_runtime.h>
#include <hip/hip_bf16.h>

#define HID 128
#define SEQ 2048
#define BATCH 64
#define NOUT 512

typedef __attribute__((ext_vector_type(8))) short bf16x8;
typedef __attribute__((ext_vector_type(4))) float f32x4;

__device__ __forceinline__ short f2bf(float f) {
    unsigned u = __float_as_uint(f);
    unsigned r = u + 0x7fffu + ((u >> 16) & 1u);   // RNE
    return (short)(r >> 16);
}

__device__ __forceinline__ float fast_sigmoid(float x) {
    return 1.0f / (1.0f + __expf(-x));
}

__device__ __forceinline__ float fast_tanh(float x) {
    return 1.0f - 2.0f / (__expf(2.0f * x) + 1.0f);
}

// ---------------------------------------------------------------------------
// GRU recurrence. One block per batch element (64 blocks -> 64 CUs).
// 256 threads = 4 waves = 1 wave/SIMD. Thread (h = tid>>1, s = tid&1) owns
// ALL THREE gate rows {h, 128+h, 256+h} of W_hh over a 64-col slice
// (192 f32 weights in VGPRs). Per step:
//   - 192 FMAs against the h-slice (LDS broadcast reads, 2-way = free)
//   - cross-slice reduce = ONE __shfl_xor(.,1) per gate (lane pairs) --
//     no LDS partial round-trip, no serial 128-thread gate phase
//   - every lane redundantly finishes sigmoid/tanh/update for its h
//   - double-buffered hbuf => ONE barrier per step (was two)
//   - raw s_barrier + lgkmcnt(0) only: the per-step global bf16 store is
//     NOT drained (default __syncthreads emits vmcnt(0) -> ~200cy/step tax)
// ---------------------------------------------------------------------------
__global__ __launch_bounds__(256, 1) void gru_seq(
    const float* __restrict__ latent,   // [BATCH][HID]
    const float* __restrict__ W_hh,     // [3*HID][HID]
    const float* __restrict__ b_ih,     // [3*HID]
    const float* __restrict__ b_hh,     // [3*HID]
    __hip_bfloat16* __restrict__ hs)    // [BATCH][SEQ][HID]  (bf16)
{
    const int b   = blockIdx.x;
    const int tid = threadIdx.x;        // 0..255
    const int h   = tid >> 1;           // 0..127
    const int s   = tid & 1;            // col half: 0 -> cols 0..63, 1 -> 64..127

    __shared__ __align__(16) float hbuf[2][HID];

    // 192 weights per thread -> VGPRs
    float wr[64], wz[64], wn[64];
    {
        const float4* pr = (const float4*)(W_hh + (size_t)h * HID + s * 64);
        const float4* pz = (const float4*)(W_hh + (size_t)(h + HID) * HID + s * 64);
        const float4* pn = (const float4*)(W_hh + (size_t)(h + 2 * HID) * HID + s * 64);
        #pragma unroll
        for (int k4 = 0; k4 < 16; k4++) {
            float4 v;
            v = pr[k4];
            wr[4 * k4 + 0] = v.x; wr[4 * k4 + 1] = v.y;
            wr[4 * k4 + 2] = v.z; wr[4 * k4 + 3] = v.w;
            v = pz[k4];
            wz[4 * k4 + 0] = v.x; wz[4 * k4 + 1] = v.y;
            wz[4 * k4 + 2] = v.z; wz[4 * k4 + 3] = v.w;
            v = pn[k4];
            wn[4 * k4 + 0] = v.x; wn[4 * k4 + 1] = v.y;
            wn[4 * k4 + 2] = v.z; wn[4 * k4 + 3] = v.w;
        }
    }
    // fold biases: r = sig(cr + dot_r), z = sig(cz + dot_z),
    // n = tanh(bin + r*(dot_n + bhn))
    const float cr  = b_ih[h] + b_hh[h];
    const float cz  = b_ih[HID + h] + b_hh[HID + h];
    const float bin = b_ih[2 * HID + h];
    const float bhn = b_hh[2 * HID + h];

    if (tid < HID) hbuf[0][tid] = latent[b * HID + tid];
    __syncthreads();

    __hip_bfloat16* out_row = hs + (size_t)b * SEQ * HID;

    int p = 0;
    for (int t = 0; t < SEQ; t++) {
        float ar = 0.f, az = 0.f, an = 0.f;
        const float4* h4 = (const float4*)&hbuf[p][s * 64];
        #pragma unroll
        for (int k4 = 0; k4 < 16; k4++) {
            float4 hv = h4[k4];                   // 2 distinct addrs/wave: free
            ar = fmaf(hv.x, wr[4 * k4 + 0], ar);
            ar = fmaf(hv.y, wr[4 * k4 + 1], ar);
            ar = fmaf(hv.z, wr[4 * k4 + 2], ar);
            ar = fmaf(hv.w, wr[4 * k4 + 3], ar);
            az = fmaf(hv.x, wz[4 * k4 + 0], az);
            az = fmaf(hv.y, wz[4 * k4 + 1], az);
            az = fmaf(hv.z, wz[4 * k4 + 2], az);
            az = fmaf(hv.w, wz[4 * k4 + 3], az);
            an = fmaf(hv.x, wn[4 * k4 + 0], an);
            an = fmaf(hv.y, wn[4 * k4 + 1], an);
            an = fmaf(hv.z, wn[4 * k4 + 2], an);
            an = fmaf(hv.w, wn[4 * k4 + 3], an);
        }
        // cross-slice reduce within the lane pair
        ar += __shfl_xor(ar, 1);
        az += __shfl_xor(az, 1);
        an += __shfl_xor(an, 1);

        float hold = hbuf[p][h];
        float r  = fast_sigmoid(cr + ar);
        float z  = fast_sigmoid(cz + az);
        float n  = fast_tanh(bin + r * (an + bhn));
        float hn = (1.0f - z) * n + z * hold;

        if (s == 0) {
            hbuf[p ^ 1][h] = hn;                  // write buffer, no race
        } else {
            out_row[t * HID + h] =
                __builtin_bit_cast(__hip_bfloat16, (unsigned short)f2bf(hn));
        }

        // LDS-only drain + raw barrier: global history stores stay in flight
        asm volatile("s_waitcnt lgkmcnt(0)" ::: "memory");
        __builtin_amdgcn_s_barrier();
        asm volatile("" ::: "memory");
        p ^= 1;
    }
}

// ---------------------------------------------------------------------------
// Repack fc_W (f32 [512][128]) into bf16 MFMA B-fragment order:
//   wfrag[((ct*4 + q)*64 + lane)*8 + j] = bf16(fc_W[ct*16 + (lane&15)]
//                                                  [q*32 + (lane>>4)*8 + j])
// ---------------------------------------------------------------------------
__global__ void wprep(const float* __restrict__ fc_W,
                      __hip_bfloat16* __restrict__ wfrag)
{
    int t = blockIdx.x * 256 + threadIdx.x;      // 0..65535
    int j    = t & 7;
    int lane = (t >> 3) & 63;
    int q    = (t >> 9) & 3;
    int ct   = t >> 11;
    int n = ct * 16 + (lane & 15);
    int k = q * 32 + (lane >> 4) * 8 + j;
    unsigned short v = (unsigned short)f2bf(fc_W[n * HID + k]);
    wfrag[t] = __builtin_bit_cast(__hip_bfloat16, v);
}

// ---------------------------------------------------------------------------
// Projection: out[row][o] = sum_k hs[row][k] * fc_W[o][k] + fc_b[o]
// M = 131072, N = 512, K = 128. bf16 MFMA 16x16x32.
// ---------------------------------------------------------------------------
__global__ __launch_bounds__(256) void proj_mfma(
    const __hip_bfloat16* __restrict__ hsb,    // [M][128] bf16
    const __hip_bfloat16* __restrict__ wfrag,  // fragment-ordered [32][4][64][8]
    const float* __restrict__ fc_b,            // [512]
    float* __restrict__ out)                   // [M][512] f32
{
    const int lane = threadIdx.x & 63;
    const int wave = threadIdx.x >> 6;
    const int m    = lane & 15;
    const int quad = lane >> 4;

    const long r0 = ((long)blockIdx.x * 4 + wave) * 32;

    bf16x8 afrag[2][4];
    #pragma unroll
    for (int rt = 0; rt < 2; rt++) {
        #pragma unroll
        for (int q = 0; q < 4; q++) {
            const __hip_bfloat16* p =
                hsb + (r0 + rt * 16 + m) * HID + q * 32 + quad * 8;
            afrag[rt][q] = *(const bf16x8*)p;   // 16B aligned
        }
    }

    for (int ct = 0; ct < 32; ct++) {
        f32x4 acc0 = {0.f, 0.f, 0.f, 0.f};
        f32x4 acc1 = {0.f, 0.f, 0.f, 0.f};
        #pragma unroll
        for (int q = 0; q < 4; q++) {
            bf16x8 bb = *(const bf16x8*)(wfrag + ((ct * 4 + q) * 64 + lane) * 8);
            acc0 = __builtin_amdgcn_mfma_f32_16x16x32_bf16(afrag[0][q], bb, acc0, 0, 0, 0);
            acc1 = __builtin_amdgcn_mfma_f32_16x16x32_bf16(afrag[1][q], bb, acc1, 0, 0, 0);
        }
        const int col = ct * 16 + m;
        const float bias = fc_b[col];
        #pragma unroll
        for (int reg = 0; reg < 4; reg++) {
            const int row_in = quad * 4 + reg;
            out[(r0 + row_in) * NOUT + col]      = acc0[reg] + bias;
            out[(r0 + 16 + row_in) * NOUT + col] = acc1[reg] + bias;
        }
    }
}

extern "C" void kernel_launch(void* const* d_in, const int* in_sizes, int n_in,
                              void* d_out, int out_size, void* d_ws, size_t ws_size,
                              hipStream_t stream) {
    const float* latent = (const float*)d_in[0];   // (64,128)
    const float* W_hh   = (const float*)d_in[1];   // (384,128)
    const float* b_ih   = (const float*)d_in[2];   // (384,)
    const float* b_hh   = (const float*)d_in[3];   // (384,)
    const float* fc_W   = (const float*)d_in[4];   // (512,128)
    const float* fc_b   = (const float*)d_in[5];   // (512,)
    float* out = (float*)d_out;                    // (64,2048,512)

    __hip_bfloat16* hsb   = (__hip_bfloat16*)d_ws;                   // 33.5 MB
    __hip_bfloat16* wfrag = (__hip_bfloat16*)((char*)d_ws + (size_t)BATCH * SEQ * HID * 2);

    wprep<<<256, 256, 0, stream>>>(fc_W, wfrag);
    gru_seq<<<BATCH, 256, 0, stream>>>(latent, W_hh, b_ih, b_hh, hsb);

    const int M = BATCH * SEQ;                     // 131072
    proj_mfma<<<M / 128, 256, 0, stream>>>(hsb, wfrag, fc_b, out);
}

// Round 2
// 1558.664 us; speedup vs baseline: 1.2106x; 1.1649x over previous
//
#include <hip/hip_runtime.h>
#include <hip/hip_bf16.h>

#define HID 128
#define SEQ 2048
#define BATCH 64
#define NOUT 512

typedef __attribute__((ext_vector_type(8))) short bf16x8;
typedef __attribute__((ext_vector_type(4))) float f32x4;

__device__ __forceinline__ short f2bf(float f) {
    unsigned u = __float_as_uint(f);
    unsigned r = u + 0x7fffu + ((u >> 16) & 1u);   // RNE
    return (short)(r >> 16);
}

__device__ __forceinline__ float fast_sigmoid(float x) {
    return 1.0f / (1.0f + __expf(-x));
}

__device__ __forceinline__ float fast_tanh(float x) {
    return 1.0f - 2.0f / (__expf(2.0f * x) + 1.0f);
}

// lane^1 within quad: quad_perm [1,0,3,2] = 0xB1
__device__ __forceinline__ float dpp_xor1(float x) {
    int y = __builtin_amdgcn_update_dpp(0, __builtin_bit_cast(int, x),
                                        0xB1, 0xF, 0xF, true);
    return __builtin_bit_cast(float, y);
}
// lane^2 within quad: quad_perm [2,3,0,1] = 0x4E
__device__ __forceinline__ float dpp_xor2(float x) {
    int y = __builtin_amdgcn_update_dpp(0, __builtin_bit_cast(int, x),
                                        0x4E, 0xF, 0xF, true);
    return __builtin_bit_cast(float, y);
}

// ---------------------------------------------------------------------------
// GRU recurrence. One block per batch element (64 blocks -> 64 CUs).
// 512 threads = 8 waves = 2 waves/SIMD (one wave issues while the other
// sits in a latency stall -- the 1-wave/SIMD version exposed every stall).
// Thread (h = tid>>2, s = tid&3) owns all three gate rows {h,128+h,256+h}
// over a 32-col slice: 96 f32 weights, comfortably VGPR-resident.
//   - h lives in 4 padded LDS slices (stride 40 words): the 4 addresses of
//     each wave's ds_read_b128 hit banks {0-3,8-11,16-19,24-27} -> ZERO
//     bank conflicts (round-1 counter showed 3.35e7 conflict-cycles).
//   - cross-slice reduce = 2 DPP quad-perm adds (VALU, ~4cyc) instead of
//     DS-pipe shuffles (~120cyc exposed at low occupancy).
//   - h_old carried in a register (no per-step LDS re-read).
//   - one raw s_barrier/step, LDS-only drain (global stores stay in flight).
// ---------------------------------------------------------------------------
__global__ __launch_bounds__(512, 2) void gru_seq(
    const float* __restrict__ latent,   // [BATCH][HID]
    const float* __restrict__ W_hh,     // [3*HID][HID]
    const float* __restrict__ b_ih,     // [3*HID]
    const float* __restrict__ b_hh,     // [3*HID]
    __hip_bfloat16* __restrict__ hs)    // [BATCH][SEQ][HID]  (bf16)
{
    const int b   = blockIdx.x;
    const int tid = threadIdx.x;        // 0..511
    const int h   = tid >> 2;           // 0..127
    const int s   = tid & 3;            // 32-col slice index

    // 4 slices of 32 floats, slice base stride 40 words (160B, 16B-aligned;
    // bank offsets 0/8/16/24 -> disjoint bank groups for the 4 slices)
    __shared__ __align__(16) float hbuf[2][152];

    // 96 weights per thread -> VGPRs
    float wr[32], wz[32], wn[32];
    {
        const float4* pr = (const float4*)(W_hh + (size_t)h * HID + s * 32);
        const float4* pz = (const float4*)(W_hh + (size_t)(h + HID) * HID + s * 32);
        const float4* pn = (const float4*)(W_hh + (size_t)(h + 2 * HID) * HID + s * 32);
        #pragma unroll
        for (int k4 = 0; k4 < 8; k4++) {
            float4 v;
            v = pr[k4];
            wr[4 * k4 + 0] = v.x; wr[4 * k4 + 1] = v.y;
            wr[4 * k4 + 2] = v.z; wr[4 * k4 + 3] = v.w;
            v = pz[k4];
            wz[4 * k4 + 0] = v.x; wz[4 * k4 + 1] = v.y;
            wz[4 * k4 + 2] = v.z; wz[4 * k4 + 3] = v.w;
            v = pn[k4];
            wn[4 * k4 + 0] = v.x; wn[4 * k4 + 1] = v.y;
            wn[4 * k4 + 2] = v.z; wn[4 * k4 + 3] = v.w;
        }
    }
    // folded biases: r = sig(cr + ar), z = sig(cz + az),
    // n = tanh(bin + r*(an + bhn))
    const float cr  = b_ih[h] + b_hh[h];
    const float cz  = b_ih[HID + h] + b_hh[HID + h];
    const float bin = b_ih[2 * HID + h];
    const float bhn = b_hh[2 * HID + h];

    float hold = latent[b * HID + h];                  // register-carried h
    const int hword = (h >> 5) * 40 + (h & 31);        // padded slice word
    if (s == 0) hbuf[0][hword] = hold;
    __syncthreads();

    __hip_bfloat16* out_p = hs + (size_t)b * SEQ * HID + h;

    int p = 0;
    for (int t = 0; t < SEQ; t++) {
        float ar = 0.f, az = 0.f, an = 0.f;
        const float4* h4 = (const float4*)&hbuf[p][s * 40];
        #pragma unroll
        for (int k4 = 0; k4 < 8; k4++) {
            float4 hv = h4[k4];                        // conflict-free by pad
            ar = fmaf(hv.x, wr[4 * k4 + 0], ar);
            ar = fmaf(hv.y, wr[4 * k4 + 1], ar);
            ar = fmaf(hv.z, wr[4 * k4 + 2], ar);
            ar = fmaf(hv.w, wr[4 * k4 + 3], ar);
            az = fmaf(hv.x, wz[4 * k4 + 0], az);
            az = fmaf(hv.y, wz[4 * k4 + 1], az);
            az = fmaf(hv.z, wz[4 * k4 + 2], az);
            az = fmaf(hv.w, wz[4 * k4 + 3], az);
            an = fmaf(hv.x, wn[4 * k4 + 0], an);
            an = fmaf(hv.y, wn[4 * k4 + 1], an);
            an = fmaf(hv.z, wn[4 * k4 + 2], an);
            an = fmaf(hv.w, wn[4 * k4 + 3], an);
        }
        // 4-slice reduce entirely on the VALU (quad-local DPP butterflies)
        ar += dpp_xor1(ar);  az += dpp_xor1(az);  an += dpp_xor1(an);
        ar += dpp_xor2(ar);  az += dpp_xor2(az);  an += dpp_xor2(an);

        float r  = fast_sigmoid(cr + ar);
        float z  = fast_sigmoid(cz + az);
        float n  = fast_tanh(bin + r * (an + bhn));
        float hn = (1.0f - z) * n + z * hold;
        hold = hn;

        if (s == 0) {
            hbuf[p ^ 1][hword] = hn;                   // write buffer, no race
        } else if (s == 1) {
            out_p[t * HID] =
                __builtin_bit_cast(__hip_bfloat16, (unsigned short)f2bf(hn));
        }

        // LDS-only drain + raw barrier: global history stores stay in flight
        asm volatile("s_waitcnt lgkmcnt(0)" ::: "memory");
        __builtin_amdgcn_s_barrier();
        asm volatile("" ::: "memory");
        p ^= 1;
    }
}

// ---------------------------------------------------------------------------
// Repack fc_W (f32 [512][128]) into bf16 MFMA fragment order:
//   wfrag[((ct*4 + q)*64 + lane)*8 + j] = bf16(fc_W[ct*16 + (lane&15)]
//                                                  [q*32 + (lane>>4)*8 + j])
// Per-lane A- and B-fragment layouts are symmetric for 16x16x32, so this
// serves as the A operand (row = lane&15 = fc_W row n) unchanged.
// ---------------------------------------------------------------------------
__global__ void wprep(const float* __restrict__ fc_W,
                      __hip_bfloat16* __restrict__ wfrag)
{
    int t = blockIdx.x * 256 + threadIdx.x;      // 0..65535
    int j    = t & 7;
    int lane = (t >> 3) & 63;
    int q    = (t >> 9) & 3;
    int ct   = t >> 11;
    int n = ct * 16 + (lane & 15);
    int k = q * 32 + (lane >> 4) * 8 + j;
    unsigned short v = (unsigned short)f2bf(fc_W[n * HID + k]);
    wfrag[t] = __builtin_bit_cast(__hip_bfloat16, v);
}

// ---------------------------------------------------------------------------
// Projection: out[row][o] = sum_k hs[row][k] * fc_W[o][k] + fc_b[o]
// M = 131072, N = 512, K = 128. bf16 MFMA 16x16x32, OPERAND-SWAPPED:
//   mfma(A = fc_W frag, B = hs frag) -> D[row=n][col=m]
// so each lane's 4 acc regs are 4 CONSECUTIVE output columns ->
// one dwordx4 store per tile (was 4 scalar dword stores; proj was
// VMEM-issue bound at ~270us vs a ~48us write-BW roofline).
// ---------------------------------------------------------------------------
__global__ __launch_bounds__(256) void proj_mfma(
    const __hip_bfloat16* __restrict__ hsb,    // [M][128] bf16
    const __hip_bfloat16* __restrict__ wfrag,  // fragment-ordered [32][4][64][8]
    const float* __restrict__ fc_b,            // [512]
    float* __restrict__ out)                   // [M][512] f32
{
    const int lane = threadIdx.x & 63;
    const int wave = threadIdx.x >> 6;
    const int m    = lane & 15;
    const int quad = lane >> 4;

    const long r0 = ((long)blockIdx.x * 4 + wave) * 32;

    bf16x8 bfrag[2][4];                         // hs as the B operand
    #pragma unroll
    for (int rt = 0; rt < 2; rt++) {
        #pragma unroll
        for (int q = 0; q < 4; q++) {
            const __hip_bfloat16* p =
                hsb + (r0 + rt * 16 + m) * HID + q * 32 + quad * 8;
            bfrag[rt][q] = *(const bf16x8*)p;   // 16B aligned
        }
    }

    for (int ct = 0; ct < 32; ct++) {
        f32x4 acc0 = {0.f, 0.f, 0.f, 0.f};
        f32x4 acc1 = {0.f, 0.f, 0.f, 0.f};
        #pragma unroll
        for (int q = 0; q < 4; q++) {
            bf16x8 aw = *(const bf16x8*)(wfrag + ((ct * 4 + q) * 64 + lane) * 8);
            acc0 = __builtin_amdgcn_mfma_f32_16x16x32_bf16(aw, bfrag[0][q], acc0, 0, 0, 0);
            acc1 = __builtin_amdgcn_mfma_f32_16x16x32_bf16(aw, bfrag[1][q], acc1, 0, 0, 0);
        }
        const int n0 = ct * 16 + quad * 4;      // 4 consecutive out columns
        const float4 bias = *(const float4*)&fc_b[n0];
        float4 o0, o1;
        o0.x = acc0[0] + bias.x; o0.y = acc0[1] + bias.y;
        o0.z = acc0[2] + bias.z; o0.w = acc0[3] + bias.w;
        o1.x = acc1[0] + bias.x; o1.y = acc1[1] + bias.y;
        o1.z = acc1[2] + bias.z; o1.w = acc1[3] + bias.w;
        *(float4*)&out[(r0 + m) * NOUT + n0]      = o0;
        *(float4*)&out[(r0 + 16 + m) * NOUT + n0] = o1;
    }
}

extern "C" void kernel_launch(void* const* d_in, const int* in_sizes, int n_in,
                              void* d_out, int out_size, void* d_ws, size_t ws_size,
                              hipStream_t stream) {
    const float* latent = (const float*)d_in[0];   // (64,128)
    const float* W_hh   = (const float*)d_in[1];   // (384,128)
    const float* b_ih   = (const float*)d_in[2];   // (384,)
    const float* b_hh   = (const float*)d_in[3];   // (384,)
    const float* fc_W   = (const float*)d_in[4];   // (512,128)
    const float* fc_b   = (const float*)d_in[5];   // (512,)
    float* out = (float*)d_out;                    // (64,2048,512)

    __hip_bfloat16* hsb   = (__hip_bfloat16*)d_ws;                   // 33.5 MB
    __hip_bfloat16* wfrag = (__hip_bfloat16*)((char*)d_ws + (size_t)BATCH * SEQ * HID * 2);

    wprep<<<256, 256, 0, stream>>>(fc_W, wfrag);
    gru_seq<<<BATCH, 512, 0, stream>>>(latent, W_hh, b_ih, b_hh, hsb);

    const int M = BATCH * SEQ;                     // 131072
    proj_mfma<<<M / 128, 256, 0, stream>>>(hsb, wfrag, fc_b, out);
}